// Round 21
// baseline (269.799 us; speedup 1.0000x reference)
//
#include <hip/hip_runtime.h>
#include <hip/hip_bf16.h>

// Problem constants (match reference)
#define NUM_MIRNA 20000
#define NUM_GENE  30000
#define NN        50000      // total nodes
#define RR        4          // relations
#define EE        1000000    // edges
#define IN_C      128
#define HIDC      128
#define OUTC      64
#define NBASIS    10
#define NSEG      (RR * NN)  // 200000, seg = dst*4 + r
#define NSEGP     200704     // padded to 196*1024 for sortbkt block writes
#define KFUSE     640        // 4*128 aggregated blocks + 128 root block
#define SROW      512        // S row length (bf16 cols) — root block read from x

#define NBKT   256           // dst-range buckets (196 used)
#define BSH    8             // bucket = dst >> 8  (256 dsts -> 1024 segs each)
#define NBKTU  ((NN + 255) >> 8)            // 196 active buckets
#define CHUNK  1024          // bs0/bs1 work per block (14KB LDS for bs1)
#define NCHUNK ((EE + CHUNK - 1) / CHUNK)   // 977
#define PREPN  221184        // prep element count
#define PREPB  ((PREPN + 255) / 256)        // 864 prep blocks
#define PMB    ((NUM_MIRNA + 63) / 64)      // 313 proj-m blocks
#define PGB    ((NUM_GENE + 63) / 64)       // 469 proj-g blocks

typedef __attribute__((ext_vector_type(8))) short bf16x8;
typedef __attribute__((ext_vector_type(4))) float f32x4;
typedef __attribute__((ext_vector_type(2))) float f32x2;

__device__ inline ushort f2bf(float x) {
    uint u = __float_as_uint(x);
    uint r = u + 0x7fffu + ((u >> 16) & 1u);
    return (ushort)(r >> 16);
}
__device__ inline uint pack2bf(float lo, float hi) {
    return (uint)f2bf(lo) | ((uint)f2bf(hi) << 16);
}
__device__ inline f32x2 up2(uint u) {   // unpack 2 bf16 -> f32x2 (lo, hi)
    return (f32x2){__uint_as_float(u << 16), __uint_as_float(u & 0xffff0000u)};
}

// async global->LDS, 16 bytes per lane (wave-linear LDS dest)
#define GLOAD_LDS16(gsrc, ldst)                                                \
    __builtin_amdgcn_global_load_lds(                                          \
        (const __attribute__((address_space(1))) void*)(gsrc),                 \
        (__attribute__((address_space(3))) void*)(ldst), 16, 0, 0)

// ---------------------------------------------------------------------------
// device body: weight prep (range-partitioned elements)
__device__ void dev_prep(int gidx,
                         const float* lin_w_m, const float* lin_w_g,
                         const float* comp1, const float* basis1, const float* root1,
                         const float* comp2, const float* basis2, const float* root2,
                         ushort* Wtm, ushort* Wtg, ushort* Wt1s, ushort* Wt2s) {
    if (gidx < 32768) {
        int idx = gidx;
        int o = idx >> 8, k = idx & 255;
        Wtm[idx] = f2bf(lin_w_m[(size_t)k * IN_C + o]);
    } else if (gidx < 98304) {
        int idx = gidx - 32768;
        int o = idx >> 9, k = idx & 511;
        Wtg[idx] = f2bf(lin_w_g[(size_t)k * IN_C + o]);
    } else if (gidx < 180224) {
        int idx = gidx - 98304;
        int o = idx / KFUSE, k = idx % KFUSE;
        float acc;
        if (k < 512) {
            int r = k >> 7, i = k & 127;
            acc = 0.f;
#pragma unroll
            for (int b = 0; b < NBASIS; ++b)
                acc += comp1[r * NBASIS + b] * basis1[((size_t)b * 128 + i) * HIDC + o];
        } else {
            acc = root1[(size_t)(k - 512) * HIDC + o];
        }
        Wt1s[idx] = f2bf(acc);
    } else if (gidx < PREPN) {
        int idx = gidx - 180224;
        int o = idx / KFUSE, k = idx % KFUSE;
        float acc;
        if (k < 512) {
            int r = k >> 7, i = k & 127;
            acc = 0.f;
#pragma unroll
            for (int b = 0; b < NBASIS; ++b)
                acc += comp2[r * NBASIS + b] * basis2[((size_t)b * 128 + i) * OUTC + o];
        } else {
            acc = root2[(size_t)(k - 512) * OUTC + o];
        }
        Wt2s[idx] = f2bf(acc);
    }
}

// device body: bs0 bucket histogram
__device__ void dev_bs0(int blk, const int* dstA, int* bcnt, char* smem) {
    int* h = (int*)smem;
    int t = threadIdx.x;
    h[t] = 0;
    __syncthreads();
    int e0 = blk * CHUNK;
    int n = EE - e0; if (n > CHUNK) n = CHUNK;
    for (int i = t; i < n; i += 256)
        atomicAdd(&h[dstA[e0 + i] >> BSH], 1);
    __syncthreads();
    if (h[t]) atomicAdd(&bcnt[t], h[t]);
}

// init_k: bs0 (first NCHUNK blocks) + prep (next PREPB blocks)
__global__ __launch_bounds__(256) void init_k(
    const int* __restrict__ dstA, int* __restrict__ bcnt,
    const float* __restrict__ lin_w_m, const float* __restrict__ lin_w_g,
    const float* __restrict__ comp1, const float* __restrict__ basis1,
    const float* __restrict__ root1,
    const float* __restrict__ comp2, const float* __restrict__ basis2,
    const float* __restrict__ root2,
    ushort* __restrict__ Wtm, ushort* __restrict__ Wtg,
    ushort* __restrict__ Wt1s, ushort* __restrict__ Wt2s) {
    __shared__ __align__(16) char smem[1024];
    int b = blockIdx.x;
    if (b < NCHUNK) {
        dev_bs0(b, dstA, bcnt, smem);
    } else {
        int gidx = (b - NCHUNK) * 256 + threadIdx.x;
        dev_prep(gidx, lin_w_m, lin_w_g, comp1, basis1, root1,
                 comp2, basis2, root2, Wtm, Wtg, Wt1s, Wt2s);
    }
}

// ---------------------------------------------------------------------------
// parallel exclusive scan of 256 bucket counts -> bbase, bcur
__global__ void bscan_k(const int* __restrict__ bcnt, int* __restrict__ bbase,
                        int* __restrict__ bcur) {
    __shared__ int sm[NBKT];
    int t = threadIdx.x;
    int v = bcnt[t];
    sm[t] = v; __syncthreads();
    for (int off = 1; off < NBKT; off <<= 1) {
        int x = (t >= off) ? sm[t - off] : 0;
        __syncthreads();
        sm[t] += x;
        __syncthreads();
    }
    int ex = sm[t] - v;
    bbase[t] = ex;
    bcur[t]  = ex;
}

// ---------------------------------------------------------------------------
// device body: bs1 multi-split with LOCAL counting sort so global payload
// writes are coalesced (consecutive i -> consecutive addr within bucket run).
// val = (locseg(10b) << 17) | src(17b).
__device__ void dev_bs1(int blk, const int* srcA, const int* dstA, const int* et,
                        int* bcur, uint* bpay, char* smem) {
    int* h     = (int*)smem;                 // 256
    int* cur   = h + NBKT;                   // 256
    int* boff  = cur + NBKT;                 // 256
    int* lbase = boff + NBKT;                // 256
    uint* lpay = (uint*)(lbase + NBKT);      // CHUNK
    uint* spay = lpay + CHUNK;               // CHUNK
    unsigned char* lbkt = (unsigned char*)(spay + CHUNK);   // CHUNK
    unsigned char* sbkt = lbkt + CHUNK;      // CHUNK
    int t = threadIdx.x;
    h[t] = 0; cur[t] = 0;
    __syncthreads();
    int e0 = blk * CHUNK;
    int n = EE - e0; if (n > CHUNK) n = CHUNK;
    for (int i = t; i < n; i += 256) {
        int e = e0 + i;
        int d = dstA[e];
        int s2 = d * 4 + et[e];
        int b = d >> BSH;
        lpay[i] = ((uint)(s2 & 1023) << 17) | (uint)srcA[e];
        lbkt[i] = (unsigned char)b;
        atomicAdd(&h[b], 1);
    }
    __syncthreads();
    // local exclusive scan of h -> lbase; global run reservation -> boff
    lbase[t] = h[t];
    __syncthreads();
    for (int off = 1; off < NBKT; off <<= 1) {
        int x = (t >= off) ? lbase[t - off] : 0;
        __syncthreads();
        lbase[t] += x;
        __syncthreads();
    }
    {
        int inc = lbase[t];
        __syncthreads();
        lbase[t] = inc - h[t];
    }
    if (h[t]) boff[t] = atomicAdd(&bcur[t], h[t]);
    __syncthreads();
    // local scatter into sorted order
    for (int i = t; i < n; i += 256) {
        int b = lbkt[i];
        int slot = atomicAdd(&cur[b], 1);
        int sp = lbase[b] + slot;
        spay[sp] = lpay[i];
        sbkt[sp] = (unsigned char)b;
    }
    __syncthreads();
    // linear, coalesced global write
    for (int i = t; i < n; i += 256) {
        int b = sbkt[i];
        bpay[boff[b] + (i - lbase[b])] = spay[i];
    }
}

// ---------------------------------------------------------------------------
// device body: staged MFMA bf16 GEMM (A_F32 T14 split-stage or gload_lds)
template <int NT, int K, bool OUT_BF16, bool ROOTX, bool A_F32>
__device__ void dev_sgemm(const void* Av, const ushort* xroot,
                          const ushort* Wt, const float* bias,
                          void* Cout, int M, int blk, char* smem)
{
    constexpr int OC = 2 * NT * 16;
    constexpr int BK = 64;
    constexpr int NTILE = K / BK;
    constexpr int AS = ROOTX ? SROW : K;
    const ushort* A  = (const ushort*)Av;
    const float*  Af = (const float*)Av;
    ushort* As = (ushort*)smem;          // 2 x 4096 bf16 = 16KB

    const int tid  = threadIdx.x;
    const int lane = tid & 63;
    const int wid  = tid >> 6;
    const int wm   = wid >> 1;
    const int wn   = wid & 1;
    const int l15  = lane & 15;
    const int lg   = lane >> 4;
    const int rowBase = blk * 64;
    const int colBase = wn * NT * 16;

    f32x4 acc[2][NT];
#pragma unroll
    for (int mt = 0; mt < 2; ++mt)
#pragma unroll
        for (int nt = 0; nt < NT; ++nt)
            acc[mt][nt] = (f32x4){0.f, 0.f, 0.f, 0.f};

    float4 fA[2][2];   // in-flight fp32 stage (A_F32 path)

    auto STAGE = [&](int buf, int t) {
        const int kc = t * BK;
#pragma unroll
        for (int i = 0; i < 2; ++i) {
            int L   = i * 4096 + tid * 16;
            int row = L >> 7;
            int bs  = (L & 127) ^ ((row & 7) << 4);
            int grow = rowBase + row; if (grow >= M) grow = M - 1;
            const ushort* src;
            if (!ROOTX || kc < SROW)
                src = A + (size_t)grow * AS + kc + (bs >> 1);
            else
                src = xroot + (size_t)grow * IN_C + (kc - SROW) + (bs >> 1);
            GLOAD_LDS16(src, &As[(size_t)buf * 4096 + (L >> 1)]);
        }
    };
    auto STAGE_LOAD = [&](int t) {
        const int kc = t * BK;
#pragma unroll
        for (int i = 0; i < 2; ++i) {
            int L   = i * 4096 + tid * 16;
            int row = L >> 7;
            int bs  = (L & 127) ^ ((row & 7) << 4);
            int grow = rowBase + row; if (grow >= M) grow = M - 1;
            const float* src = Af + (size_t)grow * K + kc + (bs >> 1);
            fA[i][0] = *(const float4*)src;
            fA[i][1] = *(const float4*)(src + 4);
        }
    };
    auto STAGE_WRITE = [&](int buf) {
#pragma unroll
        for (int i = 0; i < 2; ++i) {
            int L = i * 4096 + tid * 16;
            float4 f0 = fA[i][0], f1 = fA[i][1];
            bf16x8 tv;
            tv[0] = (short)f2bf(f0.x); tv[1] = (short)f2bf(f0.y);
            tv[2] = (short)f2bf(f0.z); tv[3] = (short)f2bf(f0.w);
            tv[4] = (short)f2bf(f1.x); tv[5] = (short)f2bf(f1.y);
            tv[6] = (short)f2bf(f1.z); tv[7] = (short)f2bf(f1.w);
            *(bf16x8*)&As[(size_t)buf * 4096 + (L >> 1)] = tv;
        }
    };

    if (A_F32) { STAGE_LOAD(0); STAGE_WRITE(0); }
    else       STAGE(0, 0);
    __syncthreads();

#pragma unroll
    for (int t = 0; t < NTILE; ++t) {
        const int kc  = t * BK;
        const int buf = t & 1;

        bf16x8 bB[2][NT];
#pragma unroll
        for (int kk = 0; kk < 2; ++kk)
#pragma unroll
            for (int nt = 0; nt < NT; ++nt)
                bB[kk][nt] = *(const bf16x8*)(
                    Wt + (size_t)(colBase + nt * 16 + l15) * K + kc + kk * 32 + lg * 8);

        if (t + 1 < NTILE) {
            if (A_F32) STAGE_LOAD(t + 1);
            else       STAGE(buf ^ 1, t + 1);
        }

        bf16x8 aF[2][2];
#pragma unroll
        for (int mt = 0; mt < 2; ++mt)
#pragma unroll
            for (int kk = 0; kk < 2; ++kk) {
                int row = wm * 32 + mt * 16 + l15;
                int kb  = kk * 64 + lg * 16;
                aF[mt][kk] = *(const bf16x8*)&As[
                    (size_t)buf * 4096 + row * 64 + ((kb ^ ((row & 7) << 4)) >> 1)];
            }

#pragma unroll
        for (int kk = 0; kk < 2; ++kk)
#pragma unroll
            for (int nt = 0; nt < NT; ++nt)
#pragma unroll
                for (int mt = 0; mt < 2; ++mt)
                    acc[mt][nt] = __builtin_amdgcn_mfma_f32_16x16x32_bf16(
                        aF[mt][kk], bB[kk][nt], acc[mt][nt], 0, 0, 0);

        if (A_F32 && t + 1 < NTILE) STAGE_WRITE(buf ^ 1);
        __syncthreads();
    }

#pragma unroll
    for (int nt = 0; nt < NT; ++nt) {
        int n = colBase + nt * 16 + l15;
        float bv = bias ? bias[n] : 0.f;
#pragma unroll
        for (int mt = 0; mt < 2; ++mt) {
#pragma unroll
            for (int q = 0; q < 4; ++q) {
                int m = rowBase + wm * 32 + mt * 16 + lg * 4 + q;
                if (m < M) {
                    float v = acc[mt][nt][q] + bv;
                    size_t off = (size_t)m * OC + n;
                    if (OUT_BF16) ((ushort*)Cout)[off] = f2bf(v);
                    else          ((float*)Cout)[off]  = v;
                }
            }
        }
    }
}

// standalone staged GEMM kernels (fused layers)
template <int NT, int K, bool OUT_BF16, bool ROOTX, bool A_F32>
__global__ __launch_bounds__(256) void sgemm_k(
    const void* __restrict__ Av, const ushort* __restrict__ xroot,
    const ushort* __restrict__ Wt, const float* __restrict__ bias,
    void* __restrict__ Cout, int M)
{
    __shared__ __align__(16) char smem[16384];
    dev_sgemm<NT, K, OUT_BF16, ROOTX, A_F32>(Av, xroot, Wt, bias, Cout, M,
                                             blockIdx.x, smem);
}

// work_k: bs1 (NCHUNK blocks) + proj_m (PMB) + proj_g (PGB), one launch.
// 16KB arena (bs1 needs 14KB at CHUNK=1024; sgemm needs 16KB).
__global__ __launch_bounds__(256) void work_k(
    const int* __restrict__ srcA, const int* __restrict__ dstA,
    const int* __restrict__ etype, int* __restrict__ bcur,
    uint* __restrict__ bpay,
    const float* __restrict__ x_mirna, const float* __restrict__ x_gene,
    const ushort* __restrict__ Wtm, const ushort* __restrict__ Wtg,
    const float* __restrict__ lin_b_m, const float* __restrict__ lin_b_g,
    ushort* __restrict__ x0bf)
{
    __shared__ __align__(16) char smem[16384];
    int b = blockIdx.x;
    if (b < NCHUNK) {
        dev_bs1(b, srcA, dstA, etype, bcur, bpay, smem);
    } else if (b < NCHUNK + PMB) {
        dev_sgemm<4, 256, true, false, true>(
            x_mirna, nullptr, Wtm, lin_b_m, x0bf, NUM_MIRNA, b - NCHUNK, smem);
    } else {
        dev_sgemm<4, 512, true, false, true>(
            x_gene, nullptr, Wtg, lin_b_g, x0bf + (size_t)NUM_MIRNA * IN_C,
            NUM_GENE, b - NCHUNK - PMB, smem);
    }
}

// ---------------------------------------------------------------------------
// sortbkt: per-bucket counting sort + CSR metadata, one block per bucket.
// sorted[] holds BYTE offsets (src*256) for the gather.
__global__ __launch_bounds__(256) void sortbkt_k(
    const uint* __restrict__ bpay, const int* __restrict__ bbase,
    const int* __restrict__ bcnt, int* __restrict__ sorted,
    int* __restrict__ cnt, int* __restrict__ base, float* __restrict__ inv)
{
    __shared__ int hist[1024];
    __shared__ int tsum[256];
    const int b = blockIdx.x;
    const int t = threadIdx.x;
    const int segbase = b << 10;

#pragma unroll
    for (int i = 0; i < 4; ++i) hist[t + i * 256] = 0;
    __syncthreads();

    const int e0 = bbase[b];
    const int n  = bcnt[b];
    for (int i = t; i < n; i += 256)
        atomicAdd(&hist[(int)(bpay[e0 + i] >> 17)], 1);
    __syncthreads();

    int h0 = hist[t * 4], h1 = hist[t * 4 + 1], h2 = hist[t * 4 + 2], h3 = hist[t * 4 + 3];
    int s = h0 + h1 + h2 + h3;
    tsum[t] = s; __syncthreads();
    for (int off = 1; off < 256; off <<= 1) {
        int x = (t >= off) ? tsum[t - off] : 0;
        __syncthreads();
        tsum[t] += x;
        __syncthreads();
    }
    int run = (t > 0) ? tsum[t - 1] : 0;
    int b0 = run, b1 = run + h0, b2 = b1 + h1, b3 = b2 + h2;

    ((int4*)cnt)[(segbase >> 2) + t]  = make_int4(h0, h1, h2, h3);
    ((int4*)base)[(segbase >> 2) + t] = make_int4(e0 + b0, e0 + b1, e0 + b2, e0 + b3);
    ((float4*)inv)[(segbase >> 2) + t] = make_float4(
        1.0f / fmaxf((float)h0, 1.0f), 1.0f / fmaxf((float)h1, 1.0f),
        1.0f / fmaxf((float)h2, 1.0f), 1.0f / fmaxf((float)h3, 1.0f));

    hist[t * 4] = b0; hist[t * 4 + 1] = b1; hist[t * 4 + 2] = b2; hist[t * 4 + 3] = b3;
    __syncthreads();

    for (int i = t; i < n; i += 256) {
        uint val = bpay[e0 + i];
        int pos = atomicAdd(&hist[(int)(val >> 17)], 1);
        sorted[e0 + pos] = (int)((val & 0x1FFFFu) << 8);   // src * 256 (byte offset)
    }
}

// ---------------------------------------------------------------------------
// Aggregate x rows per (relation, dst) into S (bf16, SROW=512 cols):
// S[d][r*128+c] = inv[d*4+r] * sum_{e in seg(d,r)} x[src_e][c]
// One wave per dst; 4 relations in lockstep; guarded loads (R13-proven
// structure) with byte-offset sorted[] (no per-load multiply).
__global__ __launch_bounds__(256) void gatherS_k(
    const ushort* __restrict__ x, const int* __restrict__ sorted,
    const int* __restrict__ base, const int* __restrict__ cnt,
    const float* __restrict__ inv, ushort* __restrict__ S)
{
    int d = (blockIdx.x * 256 + threadIdx.x) >> 6;
    int lane = threadIdx.x & 63;
    if (d >= NN) return;
    const char* xb = (const char*)x;
    uint4* Sp = (uint4*)S;               // 64 uint4 per 512-col row
    const int slot = lane >> 4;          // 0..3
    const int cg   = lane & 15;          // uint4 index within row
    const int cgb  = cg << 4;            // byte offset within row

    int4   b4 = ((const int4*)base)[d];
    int4   c4 = ((const int4*)cnt)[d];
    float4 w4 = ((const float4*)inv)[d];
    const int ofr[4]  = {0, b4.y - b4.x, b4.z - b4.x, b4.w - b4.x};
    const int cnts[4] = {c4.x, c4.y, c4.z, c4.w};
    const float wts[4] = {w4.x, w4.y, w4.z, w4.w};
    const int tot = (b4.w + c4.w) - b4.x;

    f32x2 acc[4][4];
#pragma unroll
    for (int r = 0; r < 4; ++r)
#pragma unroll
        for (int t = 0; t < 4; ++t) acc[r][t] = (f32x2){0.f, 0.f};

    if (tot <= 64) {
        int idx = sorted[b4.x + lane];   // padded window of byte offsets
        int maxn = max(max(cnts[0], cnts[1]), max(cnts[2], cnts[3]));
        for (int j = 0; j < maxn; j += 4) {
            int e = j + slot;
#pragma unroll
            for (int r = 0; r < 4; ++r) {
                int off = __shfl(idx, ofr[r] + e);
                if (e < cnts[r]) {
                    uint4 v = *(const uint4*)(xb + off + cgb);
                    acc[r][0] += up2(v.x);
                    acc[r][1] += up2(v.y);
                    acc[r][2] += up2(v.z);
                    acc[r][3] += up2(v.w);
                }
            }
        }
    } else {
        // rare fallback: per-segment chunked processing
#pragma unroll
        for (int r = 0; r < 4; ++r) {
            int s0 = b4.x + ofr[r];
            int s1 = s0 + cnts[r];
            for (int i0 = s0; i0 < s1; i0 += 64) {
                int idx2 = sorted[i0 + lane];   // padded
                int n2 = s1 - i0; if (n2 > 64) n2 = 64;
                for (int j = 0; j < n2; j += 4) {
                    int e = j + slot;
                    int off = __shfl(idx2, e);
                    if (e < n2) {
                        uint4 v = *(const uint4*)(xb + off + cgb);
                        acc[r][0] += up2(v.x);
                        acc[r][1] += up2(v.y);
                        acc[r][2] += up2(v.z);
                        acc[r][3] += up2(v.w);
                    }
                }
            }
        }
    }

#pragma unroll
    for (int r = 0; r < 4; ++r) {
        float wt = wts[r];
#pragma unroll
        for (int t = 0; t < 4; ++t) {
            acc[r][t].x += __shfl_xor(acc[r][t].x, 16);
            acc[r][t].y += __shfl_xor(acc[r][t].y, 16);
            acc[r][t].x += __shfl_xor(acc[r][t].x, 32);
            acc[r][t].y += __shfl_xor(acc[r][t].y, 32);
        }
        if (slot == 0) {
            uint4 o;
            o.x = pack2bf(acc[r][0].x * wt, acc[r][0].y * wt);
            o.y = pack2bf(acc[r][1].x * wt, acc[r][1].y * wt);
            o.z = pack2bf(acc[r][2].x * wt, acc[r][2].y * wt);
            o.w = pack2bf(acc[r][3].x * wt, acc[r][3].y * wt);
            Sp[(size_t)d * 64 + r * 16 + cg] = o;
        }
    }
}

// ---------------------------------------------------------------------------
extern "C" void kernel_launch(void* const* d_in, const int* in_sizes, int n_in,
                              void* d_out, int out_size, void* d_ws, size_t ws_size,
                              hipStream_t stream) {
    const float* x_mirna = (const float*)d_in[0];
    const float* x_gene  = (const float*)d_in[1];
    const int*   eidx    = (const int*)d_in[2];
    const int*   etype   = (const int*)d_in[3];
    const float* lin_w_m = (const float*)d_in[4];
    const float* lin_b_m = (const float*)d_in[5];
    const float* lin_w_g = (const float*)d_in[6];
    const float* lin_b_g = (const float*)d_in[7];
    const float* comp1   = (const float*)d_in[8];
    const float* basis1  = (const float*)d_in[9];
    const float* root1   = (const float*)d_in[10];
    const float* bias1   = (const float*)d_in[11];
    const float* comp2   = (const float*)d_in[12];
    const float* basis2  = (const float*)d_in[13];
    const float* root2   = (const float*)d_in[14];
    const float* bias2   = (const float*)d_in[15];

    const int* srcA = eidx;
    const int* dstA = eidx + EE;

    // workspace layout (bytes)
    char* p = (char*)d_ws;
    ushort* x0bf = (ushort*)p; p += (size_t)(NN + 1) * IN_C * 2;
    ushort* x1bf = (ushort*)p; p += (size_t)(NN + 1) * HIDC * 2;
    ushort* S    = (ushort*)p; p += (size_t)NN * SROW * 2;         // 51.2 MB
    ushort* Wtm  = (ushort*)p; p += (size_t)IN_C * 256 * 2;
    ushort* Wtg  = (ushort*)p; p += (size_t)IN_C * 512 * 2;
    ushort* Wt1s = (ushort*)p; p += (size_t)HIDC * KFUSE * 2;
    ushort* Wt2s = (ushort*)p; p += (size_t)OUTC * KFUSE * 2;
    float* inv   = (float*)p;  p += (size_t)NSEGP * 4;
    int* cnt     = (int*)p;    p += (size_t)NSEGP * 4;
    int* base    = (int*)p;    p += (size_t)NSEGP * 4;
    int* bcnt    = (int*)p;    p += NBKT * 4;
    int* bbase   = (int*)p;    p += NBKT * 4;
    int* bcur    = (int*)p;    p += NBKT * 4;
    int* sorted  = (int*)p;    p += (size_t)(EE + 64) * 4;         // +pad
    uint* bpay   = (uint*)p;   p += (size_t)EE * 4;

    float* outp = (float*)d_out;

    hipMemsetAsync(bcnt, 0, NBKT * sizeof(int), stream);

    // bs0 + all weight prep in one launch
    init_k<<<NCHUNK + PREPB, 256, 0, stream>>>(
        dstA, bcnt, lin_w_m, lin_w_g, comp1, basis1, root1,
        comp2, basis2, root2, Wtm, Wtg, Wt1s, Wt2s);

    bscan_k<<<1, NBKT, 0, stream>>>(bcnt, bbase, bcur);

    // bs1 + both input projections in one launch (mutually independent)
    work_k<<<NCHUNK + PMB + PGB, 256, 0, stream>>>(
        srcA, dstA, etype, bcur, bpay, x_mirna, x_gene,
        Wtm, Wtg, lin_b_m, lin_b_g, x0bf);

    sortbkt_k<<<NBKTU, 256, 0, stream>>>(bpay, bbase, bcnt, sorted, cnt, base, inv);

    // layer 1: aggregate x0 -> S, then fused [rel GEMMs + root + bias]
    gatherS_k<<<(NN * 64 + 255) / 256, 256, 0, stream>>>(x0bf, sorted, base, cnt, inv, S);
    sgemm_k<4, KFUSE, true, true, false><<<dim3((NN + 63) / 64), 256, 0, stream>>>(
        S, x0bf, Wt1s, bias1, x1bf, NN);

    // layer 2: aggregate x1 -> S, fused GEMM -> out (fp32)
    gatherS_k<<<(NN * 64 + 255) / 256, 256, 0, stream>>>(x1bf, sorted, base, cnt, inv, S);
    sgemm_k<2, KFUSE, false, true, false><<<dim3((NN + 63) / 64), 256, 0, stream>>>(
        S, x1bf, Wt2s, bias2, outp, NN);
}

// Round 22
// 252.378 us; speedup vs baseline: 1.0690x; 1.0690x over previous
//
#include <hip/hip_runtime.h>
#include <hip/hip_bf16.h>

// Problem constants (match reference)
#define NUM_MIRNA 20000
#define NUM_GENE  30000
#define NN        50000      // total nodes
#define RR        4          // relations
#define EE        1000000    // edges
#define IN_C      128
#define HIDC      128
#define OUTC      64
#define NBASIS    10
#define NSEG      (RR * NN)  // 200000, seg = dst*4 + r
#define NSEGP     200704     // padded to 196*1024 for sortbkt block writes
#define KFUSE     640        // 4*128 aggregated blocks + 128 root block
#define SROW      512        // S row length (bf16 cols) — root block read from x

#define NBKT   256           // dst-range buckets (196 used)
#define BSH    8             // bucket = dst >> 8  (256 dsts -> 1024 segs each)
#define NBKTU  ((NN + 255) >> 8)            // 196 active buckets
#define CHUNK  2048          // bs0/bs1 work per block (13.3KB LDS for bs1)
#define NCHUNK ((EE + CHUNK - 1) / CHUNK)   // 489
#define PREPN  221184        // prep element count
#define PREPB  ((PREPN + 255) / 256)        // 864 prep blocks
#define PMB    ((NUM_MIRNA + 63) / 64)      // 313 proj-m blocks
#define PGB    ((NUM_GENE + 63) / 64)       // 469 proj-g blocks

typedef __attribute__((ext_vector_type(8))) short bf16x8;
typedef __attribute__((ext_vector_type(4))) float f32x4;
typedef __attribute__((ext_vector_type(2))) float f32x2;

__device__ inline ushort f2bf(float x) {
    uint u = __float_as_uint(x);
    uint r = u + 0x7fffu + ((u >> 16) & 1u);
    return (ushort)(r >> 16);
}
__device__ inline uint pack2bf(float lo, float hi) {
    return (uint)f2bf(lo) | ((uint)f2bf(hi) << 16);
}
__device__ inline f32x2 up2(uint u) {   // unpack 2 bf16 -> f32x2 (lo, hi)
    return (f32x2){__uint_as_float(u << 16), __uint_as_float(u & 0xffff0000u)};
}

// async global->LDS, 16 bytes per lane (wave-linear LDS dest)
#define GLOAD_LDS16(gsrc, ldst)                                                \
    __builtin_amdgcn_global_load_lds(                                          \
        (const __attribute__((address_space(1))) void*)(gsrc),                 \
        (__attribute__((address_space(3))) void*)(ldst), 16, 0, 0)

// ---------------------------------------------------------------------------
// device body: weight prep (range-partitioned elements)
__device__ void dev_prep(int gidx,
                         const float* lin_w_m, const float* lin_w_g,
                         const float* comp1, const float* basis1, const float* root1,
                         const float* comp2, const float* basis2, const float* root2,
                         ushort* Wtm, ushort* Wtg, ushort* Wt1s, ushort* Wt2s) {
    if (gidx < 32768) {
        int idx = gidx;
        int o = idx >> 8, k = idx & 255;
        Wtm[idx] = f2bf(lin_w_m[(size_t)k * IN_C + o]);
    } else if (gidx < 98304) {
        int idx = gidx - 32768;
        int o = idx >> 9, k = idx & 511;
        Wtg[idx] = f2bf(lin_w_g[(size_t)k * IN_C + o]);
    } else if (gidx < 180224) {
        int idx = gidx - 98304;
        int o = idx / KFUSE, k = idx % KFUSE;
        float acc;
        if (k < 512) {
            int r = k >> 7, i = k & 127;
            acc = 0.f;
#pragma unroll
            for (int b = 0; b < NBASIS; ++b)
                acc += comp1[r * NBASIS + b] * basis1[((size_t)b * 128 + i) * HIDC + o];
        } else {
            acc = root1[(size_t)(k - 512) * HIDC + o];
        }
        Wt1s[idx] = f2bf(acc);
    } else if (gidx < PREPN) {
        int idx = gidx - 180224;
        int o = idx / KFUSE, k = idx % KFUSE;
        float acc;
        if (k < 512) {
            int r = k >> 7, i = k & 127;
            acc = 0.f;
#pragma unroll
            for (int b = 0; b < NBASIS; ++b)
                acc += comp2[r * NBASIS + b] * basis2[((size_t)b * 128 + i) * OUTC + o];
        } else {
            acc = root2[(size_t)(k - 512) * OUTC + o];
        }
        Wt2s[idx] = f2bf(acc);
    }
}

// device body: bs0 bucket histogram
__device__ void dev_bs0(int blk, const int* dstA, int* bcnt, char* smem) {
    int* h = (int*)smem;
    int t = threadIdx.x;
    h[t] = 0;
    __syncthreads();
    int e0 = blk * CHUNK;
    int n = EE - e0; if (n > CHUNK) n = CHUNK;
    for (int i = t; i < n; i += 256)
        atomicAdd(&h[dstA[e0 + i] >> BSH], 1);
    __syncthreads();
    if (h[t]) atomicAdd(&bcnt[t], h[t]);
}

// init_k: bs0 (first NCHUNK blocks) + prep (next PREPB blocks)
__global__ __launch_bounds__(256) void init_k(
    const int* __restrict__ dstA, int* __restrict__ bcnt,
    const float* __restrict__ lin_w_m, const float* __restrict__ lin_w_g,
    const float* __restrict__ comp1, const float* __restrict__ basis1,
    const float* __restrict__ root1,
    const float* __restrict__ comp2, const float* __restrict__ basis2,
    const float* __restrict__ root2,
    ushort* __restrict__ Wtm, ushort* __restrict__ Wtg,
    ushort* __restrict__ Wt1s, ushort* __restrict__ Wt2s) {
    __shared__ __align__(16) char smem[1024];
    int b = blockIdx.x;
    if (b < NCHUNK) {
        dev_bs0(b, dstA, bcnt, smem);
    } else {
        int gidx = (b - NCHUNK) * 256 + threadIdx.x;
        dev_prep(gidx, lin_w_m, lin_w_g, comp1, basis1, root1,
                 comp2, basis2, root2, Wtm, Wtg, Wt1s, Wt2s);
    }
}

// ---------------------------------------------------------------------------
// parallel exclusive scan of 256 bucket counts -> bbase, bcur
__global__ void bscan_k(const int* __restrict__ bcnt, int* __restrict__ bbase,
                        int* __restrict__ bcur) {
    __shared__ int sm[NBKT];
    int t = threadIdx.x;
    int v = bcnt[t];
    sm[t] = v; __syncthreads();
    for (int off = 1; off < NBKT; off <<= 1) {
        int x = (t >= off) ? sm[t - off] : 0;
        __syncthreads();
        sm[t] += x;
        __syncthreads();
    }
    int ex = sm[t] - v;
    bbase[t] = ex;
    bcur[t]  = ex;
}

// ---------------------------------------------------------------------------
// device body: bs1 multi-split into bucket-contiguous PACKED payload
// val = (locseg(10b) << 17) | src(17b); bucket in a byte sidecar (LDS).
__device__ void dev_bs1(int blk, const int* srcA, const int* dstA, const int* et,
                        int* bcur, uint* bpay, char* smem) {
    int* h    = (int*)smem;            // 256
    int* cur  = h + NBKT;              // 256
    int* boff = cur + NBKT;            // 256
    uint* lpay = (uint*)(boff + NBKT); // CHUNK
    unsigned char* lbkt = (unsigned char*)(lpay + CHUNK);  // CHUNK
    int t = threadIdx.x;
    h[t] = 0; cur[t] = 0;
    __syncthreads();
    int e0 = blk * CHUNK;
    int n = EE - e0; if (n > CHUNK) n = CHUNK;
    for (int i = t; i < n; i += 256) {
        int e = e0 + i;
        int d = dstA[e];
        int s2 = d * 4 + et[e];
        int b = d >> BSH;
        lpay[i] = ((uint)(s2 & 1023) << 17) | (uint)srcA[e];
        lbkt[i] = (unsigned char)b;
        atomicAdd(&h[b], 1);
    }
    __syncthreads();
    if (h[t]) boff[t] = atomicAdd(&bcur[t], h[t]);
    __syncthreads();
    for (int i = t; i < n; i += 256) {
        int b = lbkt[i];
        int slot = atomicAdd(&cur[b], 1);
        bpay[boff[b] + slot] = lpay[i];
    }
}

// ---------------------------------------------------------------------------
// device body: staged MFMA bf16 GEMM (A_F32 T14 split-stage or gload_lds)
template <int NT, int K, bool OUT_BF16, bool ROOTX, bool A_F32>
__device__ void dev_sgemm(const void* Av, const ushort* xroot,
                          const ushort* Wt, const float* bias,
                          void* Cout, int M, int blk, char* smem)
{
    constexpr int OC = 2 * NT * 16;
    constexpr int BK = 64;
    constexpr int NTILE = K / BK;
    constexpr int AS = ROOTX ? SROW : K;
    const ushort* A  = (const ushort*)Av;
    const float*  Af = (const float*)Av;
    ushort* As = (ushort*)smem;          // 2 x 4096 bf16 = 16KB

    const int tid  = threadIdx.x;
    const int lane = tid & 63;
    const int wid  = tid >> 6;
    const int wm   = wid >> 1;
    const int wn   = wid & 1;
    const int l15  = lane & 15;
    const int lg   = lane >> 4;
    const int rowBase = blk * 64;
    const int colBase = wn * NT * 16;

    f32x4 acc[2][NT];
#pragma unroll
    for (int mt = 0; mt < 2; ++mt)
#pragma unroll
        for (int nt = 0; nt < NT; ++nt)
            acc[mt][nt] = (f32x4){0.f, 0.f, 0.f, 0.f};

    float4 fA[2][2];   // in-flight fp32 stage (A_F32 path)

    auto STAGE = [&](int buf, int t) {
        const int kc = t * BK;
#pragma unroll
        for (int i = 0; i < 2; ++i) {
            int L   = i * 4096 + tid * 16;
            int row = L >> 7;
            int bs  = (L & 127) ^ ((row & 7) << 4);
            int grow = rowBase + row; if (grow >= M) grow = M - 1;
            const ushort* src;
            if (!ROOTX || kc < SROW)
                src = A + (size_t)grow * AS + kc + (bs >> 1);
            else
                src = xroot + (size_t)grow * IN_C + (kc - SROW) + (bs >> 1);
            GLOAD_LDS16(src, &As[(size_t)buf * 4096 + (L >> 1)]);
        }
    };
    auto STAGE_LOAD = [&](int t) {
        const int kc = t * BK;
#pragma unroll
        for (int i = 0; i < 2; ++i) {
            int L   = i * 4096 + tid * 16;
            int row = L >> 7;
            int bs  = (L & 127) ^ ((row & 7) << 4);
            int grow = rowBase + row; if (grow >= M) grow = M - 1;
            const float* src = Af + (size_t)grow * K + kc + (bs >> 1);
            fA[i][0] = *(const float4*)src;
            fA[i][1] = *(const float4*)(src + 4);
        }
    };
    auto STAGE_WRITE = [&](int buf) {
#pragma unroll
        for (int i = 0; i < 2; ++i) {
            int L = i * 4096 + tid * 16;
            float4 f0 = fA[i][0], f1 = fA[i][1];
            bf16x8 tv;
            tv[0] = (short)f2bf(f0.x); tv[1] = (short)f2bf(f0.y);
            tv[2] = (short)f2bf(f0.z); tv[3] = (short)f2bf(f0.w);
            tv[4] = (short)f2bf(f1.x); tv[5] = (short)f2bf(f1.y);
            tv[6] = (short)f2bf(f1.z); tv[7] = (short)f2bf(f1.w);
            *(bf16x8*)&As[(size_t)buf * 4096 + (L >> 1)] = tv;
        }
    };

    if (A_F32) { STAGE_LOAD(0); STAGE_WRITE(0); }
    else       STAGE(0, 0);
    __syncthreads();

#pragma unroll
    for (int t = 0; t < NTILE; ++t) {
        const int kc  = t * BK;
        const int buf = t & 1;

        bf16x8 bB[2][NT];
#pragma unroll
        for (int kk = 0; kk < 2; ++kk)
#pragma unroll
            for (int nt = 0; nt < NT; ++nt)
                bB[kk][nt] = *(const bf16x8*)(
                    Wt + (size_t)(colBase + nt * 16 + l15) * K + kc + kk * 32 + lg * 8);

        if (t + 1 < NTILE) {
            if (A_F32) STAGE_LOAD(t + 1);
            else       STAGE(buf ^ 1, t + 1);
        }

        bf16x8 aF[2][2];
#pragma unroll
        for (int mt = 0; mt < 2; ++mt)
#pragma unroll
            for (int kk = 0; kk < 2; ++kk) {
                int row = wm * 32 + mt * 16 + l15;
                int kb  = kk * 64 + lg * 16;
                aF[mt][kk] = *(const bf16x8*)&As[
                    (size_t)buf * 4096 + row * 64 + ((kb ^ ((row & 7) << 4)) >> 1)];
            }

#pragma unroll
        for (int kk = 0; kk < 2; ++kk)
#pragma unroll
            for (int nt = 0; nt < NT; ++nt)
#pragma unroll
                for (int mt = 0; mt < 2; ++mt)
                    acc[mt][nt] = __builtin_amdgcn_mfma_f32_16x16x32_bf16(
                        aF[mt][kk], bB[kk][nt], acc[mt][nt], 0, 0, 0);

        if (A_F32 && t + 1 < NTILE) STAGE_WRITE(buf ^ 1);
        __syncthreads();
    }

#pragma unroll
    for (int nt = 0; nt < NT; ++nt) {
        int n = colBase + nt * 16 + l15;
        float bv = bias ? bias[n] : 0.f;
#pragma unroll
        for (int mt = 0; mt < 2; ++mt) {
#pragma unroll
            for (int q = 0; q < 4; ++q) {
                int m = rowBase + wm * 32 + mt * 16 + lg * 4 + q;
                if (m < M) {
                    float v = acc[mt][nt][q] + bv;
                    size_t off = (size_t)m * OC + n;
                    if (OUT_BF16) ((ushort*)Cout)[off] = f2bf(v);
                    else          ((float*)Cout)[off]  = v;
                }
            }
        }
    }
}

// standalone staged GEMM kernels (fused layers)
template <int NT, int K, bool OUT_BF16, bool ROOTX, bool A_F32>
__global__ __launch_bounds__(256) void sgemm_k(
    const void* __restrict__ Av, const ushort* __restrict__ xroot,
    const ushort* __restrict__ Wt, const float* __restrict__ bias,
    void* __restrict__ Cout, int M)
{
    __shared__ __align__(16) char smem[16384];
    dev_sgemm<NT, K, OUT_BF16, ROOTX, A_F32>(Av, xroot, Wt, bias, Cout, M,
                                             blockIdx.x, smem);
}

// work_k: bs1 (NCHUNK blocks) + proj_m (PMB) + proj_g (PGB), one launch.
// 16KB arena (bs1 needs 13.3KB at CHUNK=2048; sgemm needs 16KB).
__global__ __launch_bounds__(256) void work_k(
    const int* __restrict__ srcA, const int* __restrict__ dstA,
    const int* __restrict__ etype, int* __restrict__ bcur,
    uint* __restrict__ bpay,
    const float* __restrict__ x_mirna, const float* __restrict__ x_gene,
    const ushort* __restrict__ Wtm, const ushort* __restrict__ Wtg,
    const float* __restrict__ lin_b_m, const float* __restrict__ lin_b_g,
    ushort* __restrict__ x0bf)
{
    __shared__ __align__(16) char smem[16384];
    int b = blockIdx.x;
    if (b < NCHUNK) {
        dev_bs1(b, srcA, dstA, etype, bcur, bpay, smem);
    } else if (b < NCHUNK + PMB) {
        dev_sgemm<4, 256, true, false, true>(
            x_mirna, nullptr, Wtm, lin_b_m, x0bf, NUM_MIRNA, b - NCHUNK, smem);
    } else {
        dev_sgemm<4, 512, true, false, true>(
            x_gene, nullptr, Wtg, lin_b_g, x0bf + (size_t)NUM_MIRNA * IN_C,
            NUM_GENE, b - NCHUNK - PMB, smem);
    }
}

// ---------------------------------------------------------------------------
// sortbkt: per-bucket counting sort + CSR metadata, one block per bucket.
// sorted[] holds BYTE offsets (src*256) for the gather.
__global__ __launch_bounds__(256) void sortbkt_k(
    const uint* __restrict__ bpay, const int* __restrict__ bbase,
    const int* __restrict__ bcnt, int* __restrict__ sorted,
    int* __restrict__ cnt, int* __restrict__ base, float* __restrict__ inv)
{
    __shared__ int hist[1024];
    __shared__ int tsum[256];
    const int b = blockIdx.x;
    const int t = threadIdx.x;
    const int segbase = b << 10;

#pragma unroll
    for (int i = 0; i < 4; ++i) hist[t + i * 256] = 0;
    __syncthreads();

    const int e0 = bbase[b];
    const int n  = bcnt[b];
    for (int i = t; i < n; i += 256)
        atomicAdd(&hist[(int)(bpay[e0 + i] >> 17)], 1);
    __syncthreads();

    int h0 = hist[t * 4], h1 = hist[t * 4 + 1], h2 = hist[t * 4 + 2], h3 = hist[t * 4 + 3];
    int s = h0 + h1 + h2 + h3;
    tsum[t] = s; __syncthreads();
    for (int off = 1; off < 256; off <<= 1) {
        int x = (t >= off) ? tsum[t - off] : 0;
        __syncthreads();
        tsum[t] += x;
        __syncthreads();
    }
    int run = (t > 0) ? tsum[t - 1] : 0;
    int b0 = run, b1 = run + h0, b2 = b1 + h1, b3 = b2 + h2;

    ((int4*)cnt)[(segbase >> 2) + t]  = make_int4(h0, h1, h2, h3);
    ((int4*)base)[(segbase >> 2) + t] = make_int4(e0 + b0, e0 + b1, e0 + b2, e0 + b3);
    ((float4*)inv)[(segbase >> 2) + t] = make_float4(
        1.0f / fmaxf((float)h0, 1.0f), 1.0f / fmaxf((float)h1, 1.0f),
        1.0f / fmaxf((float)h2, 1.0f), 1.0f / fmaxf((float)h3, 1.0f));

    hist[t * 4] = b0; hist[t * 4 + 1] = b1; hist[t * 4 + 2] = b2; hist[t * 4 + 3] = b3;
    __syncthreads();

    for (int i = t; i < n; i += 256) {
        uint val = bpay[e0 + i];
        int pos = atomicAdd(&hist[(int)(val >> 17)], 1);
        sorted[e0 + pos] = (int)((val & 0x1FFFFu) << 8);   // src * 256 (byte offset)
    }
}

// ---------------------------------------------------------------------------
// Aggregate x rows per (relation, dst) into S (bf16, SROW=512 cols):
// S[d][r*128+c] = inv[d*4+r] * sum_{e in seg(d,r)} x[src_e][c]
// One wave per dst; 4 relations in lockstep; guarded loads (R13-proven
// structure) with byte-offset sorted[] (no per-load multiply).
__global__ __launch_bounds__(256) void gatherS_k(
    const ushort* __restrict__ x, const int* __restrict__ sorted,
    const int* __restrict__ base, const int* __restrict__ cnt,
    const float* __restrict__ inv, ushort* __restrict__ S)
{
    int d = (blockIdx.x * 256 + threadIdx.x) >> 6;
    int lane = threadIdx.x & 63;
    if (d >= NN) return;
    const char* xb = (const char*)x;
    uint4* Sp = (uint4*)S;               // 64 uint4 per 512-col row
    const int slot = lane >> 4;          // 0..3
    const int cg   = lane & 15;          // uint4 index within row
    const int cgb  = cg << 4;            // byte offset within row

    int4   b4 = ((const int4*)base)[d];
    int4   c4 = ((const int4*)cnt)[d];
    float4 w4 = ((const float4*)inv)[d];
    const int ofr[4]  = {0, b4.y - b4.x, b4.z - b4.x, b4.w - b4.x};
    const int cnts[4] = {c4.x, c4.y, c4.z, c4.w};
    const float wts[4] = {w4.x, w4.y, w4.z, w4.w};
    const int tot = (b4.w + c4.w) - b4.x;

    f32x2 acc[4][4];
#pragma unroll
    for (int r = 0; r < 4; ++r)
#pragma unroll
        for (int t = 0; t < 4; ++t) acc[r][t] = (f32x2){0.f, 0.f};

    if (tot <= 64) {
        int idx = sorted[b4.x + lane];   // padded window of byte offsets
        int maxn = max(max(cnts[0], cnts[1]), max(cnts[2], cnts[3]));
        for (int j = 0; j < maxn; j += 4) {
            int e = j + slot;
#pragma unroll
            for (int r = 0; r < 4; ++r) {
                int off = __shfl(idx, ofr[r] + e);
                if (e < cnts[r]) {
                    uint4 v = *(const uint4*)(xb + off + cgb);
                    acc[r][0] += up2(v.x);
                    acc[r][1] += up2(v.y);
                    acc[r][2] += up2(v.z);
                    acc[r][3] += up2(v.w);
                }
            }
        }
    } else {
        // rare fallback: per-segment chunked processing
#pragma unroll
        for (int r = 0; r < 4; ++r) {
            int s0 = b4.x + ofr[r];
            int s1 = s0 + cnts[r];
            for (int i0 = s0; i0 < s1; i0 += 64) {
                int idx2 = sorted[i0 + lane];   // padded
                int n2 = s1 - i0; if (n2 > 64) n2 = 64;
                for (int j = 0; j < n2; j += 4) {
                    int e = j + slot;
                    int off = __shfl(idx2, e);
                    if (e < n2) {
                        uint4 v = *(const uint4*)(xb + off + cgb);
                        acc[r][0] += up2(v.x);
                        acc[r][1] += up2(v.y);
                        acc[r][2] += up2(v.z);
                        acc[r][3] += up2(v.w);
                    }
                }
            }
        }
    }

#pragma unroll
    for (int r = 0; r < 4; ++r) {
        float wt = wts[r];
#pragma unroll
        for (int t = 0; t < 4; ++t) {
            acc[r][t].x += __shfl_xor(acc[r][t].x, 16);
            acc[r][t].y += __shfl_xor(acc[r][t].y, 16);
            acc[r][t].x += __shfl_xor(acc[r][t].x, 32);
            acc[r][t].y += __shfl_xor(acc[r][t].y, 32);
        }
        if (slot == 0) {
            uint4 o;
            o.x = pack2bf(acc[r][0].x * wt, acc[r][0].y * wt);
            o.y = pack2bf(acc[r][1].x * wt, acc[r][1].y * wt);
            o.z = pack2bf(acc[r][2].x * wt, acc[r][2].y * wt);
            o.w = pack2bf(acc[r][3].x * wt, acc[r][3].y * wt);
            Sp[(size_t)d * 64 + r * 16 + cg] = o;
        }
    }
}

// ---------------------------------------------------------------------------
extern "C" void kernel_launch(void* const* d_in, const int* in_sizes, int n_in,
                              void* d_out, int out_size, void* d_ws, size_t ws_size,
                              hipStream_t stream) {
    const float* x_mirna = (const float*)d_in[0];
    const float* x_gene  = (const float*)d_in[1];
    const int*   eidx    = (const int*)d_in[2];
    const int*   etype   = (const int*)d_in[3];
    const float* lin_w_m = (const float*)d_in[4];
    const float* lin_b_m = (const float*)d_in[5];
    const float* lin_w_g = (const float*)d_in[6];
    const float* lin_b_g = (const float*)d_in[7];
    const float* comp1   = (const float*)d_in[8];
    const float* basis1  = (const float*)d_in[9];
    const float* root1   = (const float*)d_in[10];
    const float* bias1   = (const float*)d_in[11];
    const float* comp2   = (const float*)d_in[12];
    const float* basis2  = (const float*)d_in[13];
    const float* root2   = (const float*)d_in[14];
    const float* bias2   = (const float*)d_in[15];

    const int* srcA = eidx;
    const int* dstA = eidx + EE;

    // workspace layout (bytes)
    char* p = (char*)d_ws;
    ushort* x0bf = (ushort*)p; p += (size_t)(NN + 1) * IN_C * 2;
    ushort* x1bf = (ushort*)p; p += (size_t)(NN + 1) * HIDC * 2;
    ushort* S    = (ushort*)p; p += (size_t)NN * SROW * 2;         // 51.2 MB
    ushort* Wtm  = (ushort*)p; p += (size_t)IN_C * 256 * 2;
    ushort* Wtg  = (ushort*)p; p += (size_t)IN_C * 512 * 2;
    ushort* Wt1s = (ushort*)p; p += (size_t)HIDC * KFUSE * 2;
    ushort* Wt2s = (ushort*)p; p += (size_t)OUTC * KFUSE * 2;
    float* inv   = (float*)p;  p += (size_t)NSEGP * 4;
    int* cnt     = (int*)p;    p += (size_t)NSEGP * 4;
    int* base    = (int*)p;    p += (size_t)NSEGP * 4;
    int* bcnt    = (int*)p;    p += NBKT * 4;
    int* bbase   = (int*)p;    p += NBKT * 4;
    int* bcur    = (int*)p;    p += NBKT * 4;
    int* sorted  = (int*)p;    p += (size_t)(EE + 64) * 4;         // +pad
    uint* bpay   = (uint*)p;   p += (size_t)EE * 4;

    float* outp = (float*)d_out;

    hipMemsetAsync(bcnt, 0, NBKT * sizeof(int), stream);

    // bs0 + all weight prep in one launch
    init_k<<<NCHUNK + PREPB, 256, 0, stream>>>(
        dstA, bcnt, lin_w_m, lin_w_g, comp1, basis1, root1,
        comp2, basis2, root2, Wtm, Wtg, Wt1s, Wt2s);

    bscan_k<<<1, NBKT, 0, stream>>>(bcnt, bbase, bcur);

    // bs1 + both input projections in one launch (mutually independent)
    work_k<<<NCHUNK + PMB + PGB, 256, 0, stream>>>(
        srcA, dstA, etype, bcur, bpay, x_mirna, x_gene,
        Wtm, Wtg, lin_b_m, lin_b_g, x0bf);

    sortbkt_k<<<NBKTU, 256, 0, stream>>>(bpay, bbase, bcnt, sorted, cnt, base, inv);

    // layer 1: aggregate x0 -> S, then fused [rel GEMMs + root + bias]
    gatherS_k<<<(NN * 64 + 255) / 256, 256, 0, stream>>>(x0bf, sorted, base, cnt, inv, S);
    sgemm_k<4, KFUSE, true, true, false><<<dim3((NN + 63) / 64), 256, 0, stream>>>(
        S, x0bf, Wt1s, bias1, x1bf, NN);

    // layer 2: aggregate x1 -> S, fused GEMM -> out (fp32)
    gatherS_k<<<(NN * 64 + 255) / 256, 256, 0, stream>>>(x1bf, sorted, base, cnt, inv, S);
    sgemm_k<2, KFUSE, false, true, false><<<dim3((NN + 63) / 64), 256, 0, stream>>>(
        S, x1bf, Wt2s, bias2, outp, NN);
}